// Round 1
// 840.868 us; speedup vs baseline: 1.0258x; 1.0258x over previous
//
#include <hip/hip_runtime.h>
#include <cstddef>

#define TPB 256

__device__ __forceinline__ float sigmoidf_(float x) {
  return 1.0f / (1.0f + __expf(-x));
}

// jax.image.resize bilinear 21->42, half-pixel centers, edge-renormalized
__device__ __forceinline__ void rzmap(int i, int& j0, int& j1, float& w0, float& w1) {
  if (i == 0)            { j0 = 0;  j1 = 0;  w0 = 1.0f;  w1 = 0.0f; }
  else if (i == 41)      { j0 = 20; j1 = 20; w0 = 1.0f;  w1 = 0.0f; }
  else if ((i & 1) == 0) { int k = i >> 1; j0 = k - 1; j1 = k;     w0 = 0.25f; w1 = 0.75f; }
  else                   { int k = i >> 1; j0 = k;     j1 = k + 1; w0 = 0.75f; w1 = 0.25f; }
}

// K1: per (b, group of 32 ch): gates (means -> dwconv -> GN -> sigmoid) and
// gated projection onto mb1_w. Writes a PRIVATE partial slice per group
// (plc_part[g][b][16][441]) with plain stores -- no global atomics, no memset.
__global__ __launch_bounds__(256) void k1_gate_proj(
    const float* __restrict__ FL, const float* __restrict__ scw,
    const float* __restrict__ gng, const float* __restrict__ gnb,
    const float* __restrict__ mb1w, float* __restrict__ plc_part) {
  const int g = blockIdx.x, b = blockIdx.y;
  const int tid = threadIdx.x;
  __shared__ __align__(16) float slab[32 * 441];
  __shared__ float rm[672], cm[672], ch[672], cw[672];
  __shared__ float red[16];

  const float* base = FL + ((size_t)b * 512 + g * 32) * 441;
  const float4* b4 = (const float4*)base;
  float4* sl4 = (float4*)slab;
  for (int i = tid; i < 3528; i += TPB) sl4[i] = b4[i];
  __syncthreads();

  for (int idx = tid; idx < 672; idx += TPB) {
    int c = idx / 21, l = idx - c * 21;
    const float* rowp = slab + c * 441 + l * 21;
    float sr = 0.0f;
    #pragma unroll
    for (int w = 0; w < 21; ++w) sr += rowp[w];
    rm[idx] = sr * (1.0f / 21.0f);
    const float* colp = slab + c * 441 + l;
    float sc = 0.0f;
    #pragma unroll
    for (int h = 0; h < 21; ++h) sc += colp[h * 21];
    cm[idx] = sc * (1.0f / 21.0f);
  }
  __syncthreads();

  for (int idx = tid; idx < 672; idx += TPB) {
    int c = idx / 21, l = idx - c * 21;
    const float* w7 = scw + (g * 32 + c) * 7;
    float ah = 0.0f, aw = 0.0f;
    #pragma unroll
    for (int t = 0; t < 7; ++t) {
      int ll = l + t - 3;
      if (ll >= 0 && ll < 21) {
        float wt = w7[t];
        ah += rm[c * 21 + ll] * wt;
        aw += cm[c * 21 + ll] * wt;
      }
    }
    ch[idx] = ah; cw[idx] = aw;
  }
  __syncthreads();

  float s1 = 0.0f, s2 = 0.0f, s3 = 0.0f, s4v = 0.0f;
  for (int idx = tid; idx < 672; idx += TPB) {
    float x = ch[idx], y = cw[idx];
    s1 += x; s2 += x * x; s3 += y; s4v += y * y;
  }
  #pragma unroll
  for (int off = 32; off; off >>= 1) {
    s1 += __shfl_down(s1, off); s2 += __shfl_down(s2, off);
    s3 += __shfl_down(s3, off); s4v += __shfl_down(s4v, off);
  }
  if ((tid & 63) == 0) {
    int wv = tid >> 6;
    red[wv * 4 + 0] = s1; red[wv * 4 + 1] = s2;
    red[wv * 4 + 2] = s3; red[wv * 4 + 3] = s4v;
  }
  __syncthreads();
  const float S1 = red[0] + red[4] + red[8] + red[12];
  const float S2 = red[1] + red[5] + red[9] + red[13];
  const float S3 = red[2] + red[6] + red[10] + red[14];
  const float S4 = red[3] + red[7] + red[11] + red[15];
  const float invn = 1.0f / 672.0f;
  const float mh = S1 * invn, vh = S2 * invn - mh * mh;
  const float mw = S3 * invn, vw = S4 * invn - mw * mw;
  const float ivh = rsqrtf(vh + 1e-5f), ivw = rsqrtf(vw + 1e-5f);

  for (int idx = tid; idx < 672; idx += TPB) {
    int c = idx / 21;
    float gamma = gng[g * 32 + c], beta = gnb[g * 32 + c];
    ch[idx] = sigmoidf_((ch[idx] - mh) * ivh * gamma + beta);
    cw[idx] = sigmoidf_((cw[idx] - mw) * ivw * gamma + beta);
  }
  __syncthreads();

  float* pp = plc_part + ((size_t)g * 100 + b) * 7056;  // [16][441] slice
  for (int p = tid; p < 441; p += TPB) {
    int i = p / 21, j = p - i * 21;
    float acc[16];
    #pragma unroll
    for (int o = 0; o < 16; ++o) acc[o] = 0.0f;
    #pragma unroll 4
    for (int c = 0; c < 32; ++c) {
      float v = slab[c * 441 + p] * ch[c * 21 + i] * cw[c * 21 + j];
      const float* wc = mb1w + g * 32 + c;  // uniform addresses -> s_load
      #pragma unroll
      for (int o = 0; o < 16; ++o) acc[o] += v * wc[o * 512];
    }
    #pragma unroll
    for (int o = 0; o < 16; ++o) pp[(size_t)o * 441 + p] = acc[o];
  }
}

// K1c: plc[b][16][441] = sum over the 16 channel-groups' partials.
__global__ __launch_bounds__(256) void k1c_red(
    const float* __restrict__ pp, float* __restrict__ plc) {
  int i = blockIdx.x * TPB + threadIdx.x;
  if (i >= 705600) return;
  float s = 0.0f;
  #pragma unroll
  for (int g = 0; g < 16; ++g) s += pp[(size_t)g * 705600 + i];
  plc[i] = s;
}

// K2: bilinear resize of 16-ch plc -> bn -> relu -> mb2 -> sigmoid mask; sow sums
__global__ __launch_bounds__(256) void k2_mask(
    const float* __restrict__ plc, const float* __restrict__ mb1b,
    const float* __restrict__ bng, const float* __restrict__ bnb,
    const float* __restrict__ mb2w, const float* __restrict__ mb2b,
    float* __restrict__ mask, float* __restrict__ sow) {
  const int b = blockIdx.x;
  const int p = blockIdx.y * TPB + threadIdx.x;
  float macc[5] = {0, 0, 0, 0, 0};
  if (p < 1764) {
    int y = p / 42, x = p - y * 42;
    int jy0, jy1, jx0, jx1; float wy0, wy1, wx0, wx1;
    rzmap(y, jy0, jy1, wy0, wy1);
    rzmap(x, jx0, jx1, wx0, wx1);
    const float RSQ = rsqrtf(1.0f + 1e-5f);
    const float* pb = plc + (size_t)b * 16 * 441;
    float h[16];
    #pragma unroll
    for (int o = 0; o < 16; ++o) {
      const float* po = pb + o * 441;
      float hm = wy0 * (wx0 * po[jy0 * 21 + jx0] + wx1 * po[jy0 * 21 + jx1]) +
                 wy1 * (wx0 * po[jy1 * 21 + jx0] + wx1 * po[jy1 * 21 + jx1]);
      float t = (hm + mb1b[o]) * (bng[o] * RSQ) + bnb[o];
      h[o] = t > 0.0f ? t : 0.0f;
    }
    #pragma unroll
    for (int d = 0; d < 5; ++d) {
      float acc = mb2b[d];
      #pragma unroll
      for (int o = 0; o < 16; ++o) acc += mb2w[d * 16 + o] * h[o];
      float mv = sigmoidf_(acc);
      mask[((size_t)b * 5 + d) * 1764 + p] = mv;
      macc[d] = mv;
    }
  }
  #pragma unroll
  for (int off = 32; off; off >>= 1) {
    #pragma unroll
    for (int d = 0; d < 5; ++d) macc[d] += __shfl_down(macc[d], off);
  }
  if ((threadIdx.x & 63) == 0) {
    #pragma unroll
    for (int d = 0; d < 5; ++d) atomicAdd(&sow[b * 5 + d], macc[d]);
  }
}

// K3: vec[b,c,d] = (sum_p F1[b,c,p]*mask[b,d,p]) / (sow+1e-5).
// Mask slice (35 KB/b, 3.5 MB total) is L2-resident -> read directly through
// cache; no LDS staging, no barrier, occupancy not LDS-capped.
__global__ __launch_bounds__(256) void k3_vec(
    const float* __restrict__ F1, const float* __restrict__ mask,
    const float* __restrict__ sow, const float* __restrict__ g1d,
    float* __restrict__ vec_pad, float* __restrict__ vec_r) {
  const int ct = blockIdx.x, b = blockIdx.y;
  const int wv = threadIdx.x >> 6, lane = threadIdx.x & 63;
  const int c0 = ct * 16 + wv * 4;
  const float4* f0 = (const float4*)(F1 + ((size_t)b * 640 + c0) * 1764);
  const float4* mk = (const float4*)(mask + (size_t)b * 8820);
  float a[4][5] = {};
  for (int q = lane; q < 441; q += 64) {
    float4 f[4];
    #pragma unroll
    for (int j = 0; j < 4; ++j) f[j] = f0[(size_t)j * 441 + q];
    #pragma unroll
    for (int d = 0; d < 5; ++d) {
      float4 m = mk[d * 441 + q];
      #pragma unroll
      for (int j = 0; j < 4; ++j)
        a[j][d] += f[j].x * m.x + f[j].y * m.y + f[j].z * m.z + f[j].w * m.w;
    }
  }
  #pragma unroll
  for (int off = 32; off; off >>= 1) {
    #pragma unroll
    for (int j = 0; j < 4; ++j)
      #pragma unroll
      for (int d = 0; d < 5; ++d)
        a[j][d] += __shfl_down(a[j][d], off);
  }
  if (lane == 0) {
    const float RSQ = rsqrtf(1.0f + 1e-5f);
    #pragma unroll
    for (int j = 0; j < 4; ++j) {
      #pragma unroll
      for (int d = 0; d < 5; ++d) {
        float inv = 1.0f / (sow[b * 5 + d] + 1e-5f);
        float val = a[j][d] * inv;
        int k = (c0 + j) * 5 + d;
        vec_r[(size_t)b * 3200 + k] = val;
        vec_pad[(size_t)b * 3200 + k] = val * (g1d[k] * RSQ);
      }
    }
  }
}

// K4: fp32 GEMM dacc[ks] = A(128 virtual rows) @ W^T slice.
// Block tile 128m x 64n (whole M in one block -> lin_w read from HBM ONCE),
// 512 threads, thread tile 4x4, BK=32, K-split by 10 (grid.z).
// Virtual rows folded into staging: row 100 = bn1d_b, rows 101..127 = 0.
// LDS rows padded (132/68 f4) -> conflict-free ds_read_b128 on both operands.
__global__ __launch_bounds__(512) void k4_gemm(
    const float* __restrict__ A, const float* __restrict__ b1d,
    const float* __restrict__ W, float* __restrict__ dacc) {
  const int n0 = blockIdx.x * 64, ks = blockIdx.z;
  const int tid = threadIdx.x;
  const int tx = tid & 15, ty = tid >> 4;   // compute: 16 x 32 threads
  const int lr = tid >> 3, lq = tid & 7;    // staging: 64 rows x 8 f4
  __shared__ float4 As[8 * 132];
  __shared__ float4 Ws[8 * 68];
  const float4* A4 = (const float4*)A;
  const float4* B4 = (const float4*)b1d;
  const float4* W4 = (const float4*)W;
  const int kbase = ks * 80;                // f4 columns per K-slice
  const int r1 = lr + 64;
  float acc[4][4] = {};
  for (int kk = 0; kk < 10; ++kk) {
    __syncthreads();
    const int col = kbase + kk * 8 + lq;
    As[lq * 132 + lr] = A4[(size_t)lr * 800 + col];   // rows 0..63 all real
    float4 va1;
    if (r1 < 100)       va1 = A4[(size_t)r1 * 800 + col];
    else if (r1 == 100) va1 = B4[col];                 // virtual bias row
    else                va1 = make_float4(0.f, 0.f, 0.f, 0.f);
    As[lq * 132 + r1] = va1;
    Ws[lq * 68 + lr] = W4[(size_t)(n0 + lr) * 800 + col];
    __syncthreads();
    #pragma unroll
    for (int kq = 0; kq < 8; ++kq) {
      float4 av[4], bv[4];
      #pragma unroll
      for (int r = 0; r < 4; ++r) av[r] = As[kq * 132 + ty + 32 * r];
      #pragma unroll
      for (int s = 0; s < 4; ++s) bv[s] = Ws[kq * 68 + tx + 16 * s];
      #pragma unroll
      for (int r = 0; r < 4; ++r)
        #pragma unroll
        for (int s = 0; s < 4; ++s)
          acc[r][s] += av[r].x * bv[s].x + av[r].y * bv[s].y +
                       av[r].z * bv[s].z + av[r].w * bv[s].w;
    }
  }
  float* dp = dacc + (size_t)ks * 409600;
  #pragma unroll
  for (int r = 0; r < 4; ++r) {
    const int m = ty + 32 * r;
    #pragma unroll
    for (int s = 0; s < 4; ++s)
      dp[(size_t)m * 3200 + n0 + tx + 16 * s] = acc[r][s];
  }
}

// K4b: sum 10 K-slices, add c0 (virtual row 100) + lin_b, elu, combine with
// vec; writes query rows directly and accumulates the 5-shot support mean
// via atomics into the (pre-zeroed) support rows of out.
__global__ __launch_bounds__(256) void k4b_epi(
    const float* __restrict__ dacc, const float* __restrict__ linb,
    const float* __restrict__ vec_r, float* __restrict__ out) {
  int i = blockIdx.x * TPB + threadIdx.x;
  if (i >= 320000) return;
  int m = i / 3200, n = i - m * 3200;
  const size_t S = 409600;
  size_t o = (size_t)m * 3200 + n;
  size_t oc = (size_t)100 * 3200 + n;
  float d = 0.0f, c0 = 0.0f;
  #pragma unroll
  for (int t = 0; t < 10; ++t) { d += dacc[t * S + o]; c0 += dacc[t * S + oc]; }
  float dv = d + c0 + linb[n];
  float z = dv > 0.0f ? dv : expm1f(dv);
  float ov = 0.5f * z + 0.5f * vec_r[i];
  if (m < 25) atomicAdd(out + (size_t)(m / 5) * 3200 + n, 0.2f * ov);
  else        out[(size_t)(m - 20) * 3200 + n] = ov;  // query rows 5..79
}

extern "C" void kernel_launch(void* const* d_in, const int* in_sizes, int n_in,
                              void* d_out, int out_size, void* d_ws, size_t ws_size,
                              hipStream_t stream) {
  const float* F1   = (const float*)d_in[0];
  const float* FL   = (const float*)d_in[1];
  const float* scw  = (const float*)d_in[2];
  const float* gng  = (const float*)d_in[3];
  const float* gnb  = (const float*)d_in[4];
  const float* mb1w = (const float*)d_in[5];
  const float* mb1b = (const float*)d_in[6];
  const float* bng  = (const float*)d_in[7];
  const float* bnb  = (const float*)d_in[8];
  const float* mb2w = (const float*)d_in[9];
  const float* mb2b = (const float*)d_in[10];
  const float* g1d  = (const float*)d_in[11];
  const float* b1d  = (const float*)d_in[12];
  const float* linw = (const float*)d_in[13];
  const float* linb = (const float*)d_in[14];

  float* ws       = (float*)d_ws;
  float* plc      = ws;                    // 705600
  float* plc_part = ws + 705600;           // 16*705600 = 11289600
  float* sow      = ws + 11995200;         // 512
  float* mask     = ws + 11995712;         // 882000
  float* vec_pad  = ws + 12877712;         // 100*3200 = 320000
  float* vec_r    = ws + 13197712;         // 320000
  float* dacc     = ws + 13517712;         // 10*128*3200 = 4096000
  float* out      = (float*)d_out;         // total ws ~70.5 MB

  hipMemsetAsync(sow, 0, 512 * sizeof(float), stream);
  hipMemsetAsync(out, 0, 16000 * sizeof(float), stream);  // support rows
  k1_gate_proj<<<dim3(16, 100), TPB, 0, stream>>>(FL, scw, gng, gnb, mb1w, plc_part);
  k1c_red<<<dim3(2757), TPB, 0, stream>>>(plc_part, plc);
  k2_mask<<<dim3(100, 7), TPB, 0, stream>>>(plc, mb1b, bng, bnb, mb2w, mb2b, mask, sow);
  k3_vec<<<dim3(40, 100), TPB, 0, stream>>>(F1, mask, sow, g1d, vec_pad, vec_r);
  k4_gemm<<<dim3(50, 1, 10), 512, 0, stream>>>(vec_pad, b1d, linw, dacc);
  k4b_epi<<<dim3(1250), TPB, 0, stream>>>(dacc, linb, vec_r, out);
}

// Round 3
// 827.401 us; speedup vs baseline: 1.0425x; 1.0163x over previous
//
#include <hip/hip_runtime.h>
#include <cstddef>

#define TPB 256

__device__ __forceinline__ float sigmoidf_(float x) {
  return 1.0f / (1.0f + __expf(-x));
}

// jax.image.resize bilinear 21->42, half-pixel centers, edge-renormalized
__device__ __forceinline__ void rzmap(int i, int& j0, int& j1, float& w0, float& w1) {
  if (i == 0)            { j0 = 0;  j1 = 0;  w0 = 1.0f;  w1 = 0.0f; }
  else if (i == 41)      { j0 = 20; j1 = 20; w0 = 1.0f;  w1 = 0.0f; }
  else if ((i & 1) == 0) { int k = i >> 1; j0 = k - 1; j1 = k;     w0 = 0.25f; w1 = 0.75f; }
  else                   { int k = i >> 1; j0 = k;     j1 = k + 1; w0 = 0.75f; w1 = 0.25f; }
}

// K1: per (b, PAIR of 32-ch groups): gates (means -> dwconv -> GN -> sigmoid)
// and gated projection onto mb1_w. The per-thread accumulator persists
// across the two serial slab passes -> plc_part has only 8 partials (was 16),
// halving the partial-sum HBM round-trip. Plain stores, no atomics, no memset.
__global__ __launch_bounds__(256) void k1_gate_proj(
    const float* __restrict__ FL, const float* __restrict__ scw,
    const float* __restrict__ gng, const float* __restrict__ gnb,
    const float* __restrict__ mb1w, float* __restrict__ plc_part) {
  const int gp = blockIdx.x, b = blockIdx.y;   // gp in 0..7 (pair of groups)
  const int tid = threadIdx.x;
  __shared__ __align__(16) float slab[32 * 441];
  __shared__ float rm[672], cm[672], ch[672], cw[672];
  __shared__ float red[16];

  const int p0 = tid;            // pixel 0 (always < 441)
  const int p1 = tid + 256;      // pixel 1 (valid for tid < 185)
  const int i0 = p0 / 21, j0 = p0 - i0 * 21;
  const int i1 = p1 / 21, j1 = p1 - i1 * 21;
  float acc0[16] = {}, acc1[16] = {};

  for (int gi = 0; gi < 2; ++gi) {
    const int g = gp * 2 + gi;
    __syncthreads();  // protect slab/red reuse from previous group pass

    const float4* b4 = (const float4*)(FL + ((size_t)b * 512 + g * 32) * 441);
    float4* sl4 = (float4*)slab;
    for (int i = tid; i < 3528; i += TPB) sl4[i] = b4[i];
    __syncthreads();

    for (int idx = tid; idx < 672; idx += TPB) {
      int c = idx / 21, l = idx - c * 21;
      const float* rowp = slab + c * 441 + l * 21;
      float sr = 0.0f;
      #pragma unroll
      for (int w = 0; w < 21; ++w) sr += rowp[w];
      rm[idx] = sr * (1.0f / 21.0f);
      const float* colp = slab + c * 441 + l;
      float sc = 0.0f;
      #pragma unroll
      for (int h = 0; h < 21; ++h) sc += colp[h * 21];
      cm[idx] = sc * (1.0f / 21.0f);
    }
    __syncthreads();

    for (int idx = tid; idx < 672; idx += TPB) {
      int c = idx / 21, l = idx - c * 21;
      const float* w7 = scw + (g * 32 + c) * 7;
      float ah = 0.0f, aw = 0.0f;
      #pragma unroll
      for (int t = 0; t < 7; ++t) {
        int ll = l + t - 3;
        if (ll >= 0 && ll < 21) {
          float wt = w7[t];
          ah += rm[c * 21 + ll] * wt;
          aw += cm[c * 21 + ll] * wt;
        }
      }
      ch[idx] = ah; cw[idx] = aw;
    }
    __syncthreads();

    float s1 = 0.0f, s2 = 0.0f, s3 = 0.0f, s4v = 0.0f;
    for (int idx = tid; idx < 672; idx += TPB) {
      float x = ch[idx], y = cw[idx];
      s1 += x; s2 += x * x; s3 += y; s4v += y * y;
    }
    #pragma unroll
    for (int off = 32; off; off >>= 1) {
      s1 += __shfl_down(s1, off); s2 += __shfl_down(s2, off);
      s3 += __shfl_down(s3, off); s4v += __shfl_down(s4v, off);
    }
    if ((tid & 63) == 0) {
      int wv = tid >> 6;
      red[wv * 4 + 0] = s1; red[wv * 4 + 1] = s2;
      red[wv * 4 + 2] = s3; red[wv * 4 + 3] = s4v;
    }
    __syncthreads();
    const float S1 = red[0] + red[4] + red[8] + red[12];
    const float S2 = red[1] + red[5] + red[9] + red[13];
    const float S3 = red[2] + red[6] + red[10] + red[14];
    const float S4 = red[3] + red[7] + red[11] + red[15];
    const float invn = 1.0f / 672.0f;
    const float mh = S1 * invn, vh = S2 * invn - mh * mh;
    const float mw = S3 * invn, vw = S4 * invn - mw * mw;
    const float ivh = rsqrtf(vh + 1e-5f), ivw = rsqrtf(vw + 1e-5f);

    for (int idx = tid; idx < 672; idx += TPB) {
      int c = idx / 21;
      float gamma = gng[g * 32 + c], beta = gnb[g * 32 + c];
      ch[idx] = sigmoidf_((ch[idx] - mh) * ivh * gamma + beta);
      cw[idx] = sigmoidf_((cw[idx] - mw) * ivw * gamma + beta);
    }
    __syncthreads();

    // accumulate gated projection for this group into persistent registers
    #pragma unroll 4
    for (int c = 0; c < 32; ++c) {
      float v = slab[c * 441 + p0] * ch[c * 21 + i0] * cw[c * 21 + j0];
      const float* wc = mb1w + g * 32 + c;  // uniform addresses -> s_load
      #pragma unroll
      for (int o = 0; o < 16; ++o) acc0[o] += v * wc[o * 512];
    }
    if (p1 < 441) {
      #pragma unroll 4
      for (int c = 0; c < 32; ++c) {
        float v = slab[c * 441 + p1] * ch[c * 21 + i1] * cw[c * 21 + j1];
        const float* wc = mb1w + g * 32 + c;
        #pragma unroll
        for (int o = 0; o < 16; ++o) acc1[o] += v * wc[o * 512];
      }
    }
  }

  float* pp = plc_part + ((size_t)gp * 100 + b) * 7056;  // [16][441] slice
  #pragma unroll
  for (int o = 0; o < 16; ++o) pp[(size_t)o * 441 + p0] = acc0[o];
  if (p1 < 441) {
    #pragma unroll
    for (int o = 0; o < 16; ++o) pp[(size_t)o * 441 + p1] = acc1[o];
  }
}

// K1c: plc[b][16][441] = sum over the 8 group-pair partials.
__global__ __launch_bounds__(256) void k1c_red(
    const float* __restrict__ pp, float* __restrict__ plc) {
  int i = blockIdx.x * TPB + threadIdx.x;
  if (i >= 705600) return;
  float s = 0.0f;
  #pragma unroll
  for (int g = 0; g < 8; ++g) s += pp[(size_t)g * 705600 + i];
  plc[i] = s;
}

// K2: bilinear resize of 16-ch plc -> bn -> relu -> mb2 -> sigmoid mask.
// (sow is computed inside k3 -- no atomics here.)
__global__ __launch_bounds__(256) void k2_mask(
    const float* __restrict__ plc, const float* __restrict__ mb1b,
    const float* __restrict__ bng, const float* __restrict__ bnb,
    const float* __restrict__ mb2w, const float* __restrict__ mb2b,
    float* __restrict__ mask) {
  const int b = blockIdx.x;
  const int p = blockIdx.y * TPB + threadIdx.x;
  if (p >= 1764) return;
  int y = p / 42, x = p - y * 42;
  int jy0, jy1, jx0, jx1; float wy0, wy1, wx0, wx1;
  rzmap(y, jy0, jy1, wy0, wy1);
  rzmap(x, jx0, jx1, wx0, wx1);
  const float RSQ = rsqrtf(1.0f + 1e-5f);
  const float* pb = plc + (size_t)b * 16 * 441;
  float h[16];
  #pragma unroll
  for (int o = 0; o < 16; ++o) {
    const float* po = pb + o * 441;
    float hm = wy0 * (wx0 * po[jy0 * 21 + jx0] + wx1 * po[jy0 * 21 + jx1]) +
               wy1 * (wx0 * po[jy1 * 21 + jx0] + wx1 * po[jy1 * 21 + jx1]);
    float t = (hm + mb1b[o]) * (bng[o] * RSQ) + bnb[o];
    h[o] = t > 0.0f ? t : 0.0f;
  }
  #pragma unroll
  for (int d = 0; d < 5; ++d) {
    float acc = mb2b[d];
    #pragma unroll
    for (int o = 0; o < 16; ++o) acc += mb2w[d * 16 + o] * h[o];
    mask[((size_t)b * 5 + d) * 1764 + p] = sigmoidf_(acc);
  }
}

// K3: vec[b,c,d] = (sum_p F1[b,c,p]*mask[b,d,p]) / (sow+1e-5).
// Mask slice is L2-resident -> read directly through cache. Each wave's
// q-sweep covers the ENTIRE mask slice, so sow is computed in-register
// during the same sweep (no global sow buffer, no atomics, no memset).
__global__ __launch_bounds__(256) void k3_vec(
    const float* __restrict__ F1, const float* __restrict__ mask,
    const float* __restrict__ g1d,
    float* __restrict__ vec_pad, float* __restrict__ vec_r) {
  const int ct = blockIdx.x, b = blockIdx.y;
  const int wv = threadIdx.x >> 6, lane = threadIdx.x & 63;
  const int c0 = ct * 16 + wv * 4;
  const float4* f0 = (const float4*)(F1 + ((size_t)b * 640 + c0) * 1764);
  const float4* mk = (const float4*)(mask + (size_t)b * 8820);
  float a[4][5] = {};
  float sw[5] = {};
  for (int q = lane; q < 441; q += 64) {
    float4 f[4];
    #pragma unroll
    for (int j = 0; j < 4; ++j) f[j] = f0[(size_t)j * 441 + q];
    #pragma unroll
    for (int d = 0; d < 5; ++d) {
      float4 m = mk[d * 441 + q];
      sw[d] += m.x + m.y + m.z + m.w;
      #pragma unroll
      for (int j = 0; j < 4; ++j)
        a[j][d] += f[j].x * m.x + f[j].y * m.y + f[j].z * m.z + f[j].w * m.w;
    }
  }
  #pragma unroll
  for (int off = 32; off; off >>= 1) {
    #pragma unroll
    for (int d = 0; d < 5; ++d) {
      sw[d] += __shfl_down(sw[d], off);
      #pragma unroll
      for (int j = 0; j < 4; ++j) a[j][d] += __shfl_down(a[j][d], off);
    }
  }
  if (lane == 0) {
    const float RSQ = rsqrtf(1.0f + 1e-5f);
    float inv[5];
    #pragma unroll
    for (int d = 0; d < 5; ++d) inv[d] = 1.0f / (sw[d] + 1e-5f);
    #pragma unroll
    for (int j = 0; j < 4; ++j) {
      #pragma unroll
      for (int d = 0; d < 5; ++d) {
        float val = a[j][d] * inv[d];
        int k = (c0 + j) * 5 + d;
        vec_r[(size_t)b * 3200 + k] = val;
        vec_pad[(size_t)b * 3200 + k] = val * (g1d[k] * RSQ);
      }
    }
  }
}

// K4: fp32 GEMM dacc[ks] = A(128 virtual rows) @ W^T slice.
// Block tile 128m x 64n (whole M in one block -> lin_w read from HBM ONCE),
// 512 threads, thread tile 4x4, BK=32, K-split by 10 (grid.z).
// Virtual rows folded into staging: row 100 = bn1d_b, rows 101..127 = 0.
// z==0 blocks also zero the support region of out (stream-ordered vs k4b).
__global__ __launch_bounds__(512) void k4_gemm(
    const float* __restrict__ A, const float* __restrict__ b1d,
    const float* __restrict__ W, float* __restrict__ dacc,
    float* __restrict__ outz) {
  const int n0 = blockIdx.x * 64, ks = blockIdx.z;
  const int tid = threadIdx.x;
  const int tx = tid & 15, ty = tid >> 4;   // compute: 16 x 32 threads
  const int lr = tid >> 3, lq = tid & 7;    // staging: 64 rows x 8 f4
  __shared__ float4 As[8 * 132];
  __shared__ float4 Ws[8 * 68];
  if (ks == 0) {                             // zero support rows of out
    int zi = blockIdx.x * 512 + tid;
    if (zi < 16000) outz[zi] = 0.0f;
  }
  const float4* A4 = (const float4*)A;
  const float4* B4 = (const float4*)b1d;
  const float4* W4 = (const float4*)W;
  const int kbase = ks * 80;                // f4 columns per K-slice
  const int r1 = lr + 64;
  float acc[4][4] = {};
  for (int kk = 0; kk < 10; ++kk) {
    __syncthreads();
    const int col = kbase + kk * 8 + lq;
    As[lq * 132 + lr] = A4[(size_t)lr * 800 + col];   // rows 0..63 all real
    float4 va1;
    if (r1 < 100)       va1 = A4[(size_t)r1 * 800 + col];
    else if (r1 == 100) va1 = B4[col];                 // virtual bias row
    else                va1 = make_float4(0.f, 0.f, 0.f, 0.f);
    As[lq * 132 + r1] = va1;
    Ws[lq * 68 + lr] = W4[(size_t)(n0 + lr) * 800 + col];
    __syncthreads();
    #pragma unroll
    for (int kq = 0; kq < 8; ++kq) {
      float4 av[4], bv[4];
      #pragma unroll
      for (int r = 0; r < 4; ++r) av[r] = As[kq * 132 + ty + 32 * r];
      #pragma unroll
      for (int s = 0; s < 4; ++s) bv[s] = Ws[kq * 68 + tx + 16 * s];
      #pragma unroll
      for (int r = 0; r < 4; ++r)
        #pragma unroll
        for (int s = 0; s < 4; ++s)
          acc[r][s] += av[r].x * bv[s].x + av[r].y * bv[s].y +
                       av[r].z * bv[s].z + av[r].w * bv[s].w;
    }
  }
  float* dp = dacc + (size_t)ks * 409600;
  #pragma unroll
  for (int r = 0; r < 4; ++r) {
    const int m = ty + 32 * r;
    #pragma unroll
    for (int s = 0; s < 4; ++s)
      dp[(size_t)m * 3200 + n0 + tx + 16 * s] = acc[r][s];
  }
}

// K4b: sum 10 K-slices, add c0 (virtual row 100) + lin_b, elu, combine with
// vec; writes query rows directly and accumulates the 5-shot support mean
// via atomics into the (k4-zeroed) support rows of out.
__global__ __launch_bounds__(256) void k4b_epi(
    const float* __restrict__ dacc, const float* __restrict__ linb,
    const float* __restrict__ vec_r, float* __restrict__ out) {
  int i = blockIdx.x * TPB + threadIdx.x;
  if (i >= 320000) return;
  int m = i / 3200, n = i - m * 3200;
  const size_t S = 409600;
  size_t o = (size_t)m * 3200 + n;
  size_t oc = (size_t)100 * 3200 + n;
  float d = 0.0f, c0 = 0.0f;
  #pragma unroll
  for (int t = 0; t < 10; ++t) { d += dacc[t * S + o]; c0 += dacc[t * S + oc]; }
  float dv = d + c0 + linb[n];
  float z = dv > 0.0f ? dv : expm1f(dv);
  float ov = 0.5f * z + 0.5f * vec_r[i];
  if (m < 25) atomicAdd(out + (size_t)(m / 5) * 3200 + n, 0.2f * ov);
  else        out[(size_t)(m - 20) * 3200 + n] = ov;  // query rows 5..79
}

extern "C" void kernel_launch(void* const* d_in, const int* in_sizes, int n_in,
                              void* d_out, int out_size, void* d_ws, size_t ws_size,
                              hipStream_t stream) {
  const float* F1   = (const float*)d_in[0];
  const float* FL   = (const float*)d_in[1];
  const float* scw  = (const float*)d_in[2];
  const float* gng  = (const float*)d_in[3];
  const float* gnb  = (const float*)d_in[4];
  const float* mb1w = (const float*)d_in[5];
  const float* mb1b = (const float*)d_in[6];
  const float* bng  = (const float*)d_in[7];
  const float* bnb  = (const float*)d_in[8];
  const float* mb2w = (const float*)d_in[9];
  const float* mb2b = (const float*)d_in[10];
  const float* g1d  = (const float*)d_in[11];
  const float* b1d  = (const float*)d_in[12];
  const float* linw = (const float*)d_in[13];
  const float* linb = (const float*)d_in[14];

  float* ws       = (float*)d_ws;
  float* plc      = ws;                    // 705600
  float* plc_part = ws + 705600;           // 8*705600 = 5644800
  float* mask     = ws + 6350400;          // 882000
  float* vec_pad  = ws + 7232400;          // 100*3200 = 320000
  float* vec_r    = ws + 7552400;          // 320000
  float* dacc     = ws + 7872400;          // 10*128*3200 = 4096000
  float* out      = (float*)d_out;         // total ws ~47.9 MB

  k1_gate_proj<<<dim3(8, 100), TPB, 0, stream>>>(FL, scw, gng, gnb, mb1w, plc_part);
  k1c_red<<<dim3(2757), TPB, 0, stream>>>(plc_part, plc);
  k2_mask<<<dim3(100, 7), TPB, 0, stream>>>(plc, mb1b, bng, bnb, mb2w, mb2b, mask);
  k3_vec<<<dim3(40, 100), TPB, 0, stream>>>(F1, mask, g1d, vec_pad, vec_r);
  k4_gemm<<<dim3(50, 1, 10), 512, 0, stream>>>(vec_pad, b1d, linw, dacc, out);
  k4b_epi<<<dim3(1250), TPB, 0, stream>>>(dacc, linb, vec_r, out);
}